// Round 16
// baseline (104.914 us; speedup 1.0000x reference)
//
#include <hip/hip_runtime.h>

#define B_ 2
#define T_ 2048
#define H_ 12
#define E_ 64
#define M_ 256
#define NBLK 32

typedef _Float16 f16;
typedef f16 f16x4 __attribute__((ext_vector_type(4)));
typedef f16 f16x8 __attribute__((ext_vector_type(8)));
typedef float f32x4 __attribute__((ext_vector_type(4)));

#define MFMA16(Av, Bv, Cv) __builtin_amdgcn_mfma_f32_16x16x32_f16(Av, Bv, Cv, 0, 0, 0)

constexpr float DN = 0.35355339059327373f;        // sqrt(temp)
constexpr float HALF_LOG_M = 2.7725887222397811f; // 0.5*ln(256)
constexpr float LN_CQ = 5.545177444479562f;       // ln(256): q' scale
constexpr float LN_CK = 2.772588722239781f;       // ln(16):  k' scale

__device__ __forceinline__ unsigned fkey(float f) {
  unsigned u = __float_as_uint(f);
  return (u & 0x80000000u) ? ~u : (u | 0x80000000u);
}
__device__ __forceinline__ float unfkey(unsigned k) {
  return (k & 0x80000000u) ? __uint_as_float(k & 0x7fffffffu) : __uint_as_float(~k);
}

// ---------------- workspace layout (bytes) ----------------
// 0         : skb     uint[24]                        (pad 256)
// 256       : projh   f16 [256][64]         32768 ->     33024
// 33024     : ksh     f16 [24][2048][64]  6291456 ->   6324480
// 6324480   : kd      f32 [24][2048]       196608 ->   6521088
// 6521088   : k_prime f16 [24][2048][256] 25165824 -> 31686912
// 31686912  : vTT     f16 [24][64][2048]  6291456 ->  37978368
// 37978368  : kvacc8  f32 [8][24][65][256] 12779520 -> 50757888
// 50757888  : kvT     f16 [24][80][256]     983040 ->  51740928  (< proven 52.13 MB)
#define PSTRIDEF 399360  // 24*65*256 floats per partial

__global__ void init_ws(unsigned* __restrict__ skb, f16* __restrict__ projh,
                        const float* __restrict__ proj) {
  int i = blockIdx.x * blockDim.x + threadIdx.x;
  if (i < B_ * H_) skb[i] = 0u;
  if (i < M_ * E_) projh[i] = (f16)proj[i];
}

// prep_k: store ksh (DN-scaled f16) + kd (f32); GEMM k_dash; global max -> skb
__global__ __launch_bounds__(512) void prep_k(
    const float* __restrict__ key, const f16* __restrict__ projh,
    unsigned* __restrict__ skb, f16* __restrict__ ksh, float* __restrict__ kd) {
  __shared__ float red[8];
  const int blk = blockIdx.x;  // 24 bh x 8 chunks
  const int chunk = blk & 7, bh = blk >> 3;
  const int b = bh / H_, h = bh % H_;
  const int t = threadIdx.x;
  const int w = t >> 6, l = t & 63, l15 = l & 15, g4 = l >> 4;
  const int rblk = w & 3, cH = w >> 2, r0 = rblk * 16;
  float lmax = -3.0e38f;

  for (int ti = 0; ti < 4; ++ti) {
    const int t0 = chunk * 256 + ti * 64;
    const int trow = t0 + r0 + l15;
    f16x8 avk[2];
    float kdl = 0.f;
    const float* gk = key + (((size_t)b * T_ + trow) * H_ + h) * E_;
#pragma unroll
    for (int kk = 0; kk < 2; ++kk) {
      int e0 = kk * 32 + g4 * 8;
      f32x4 a = *(const f32x4*)(gk + e0);
      f32x4 bq = *(const f32x4*)(gk + e0 + 4);
      float x0 = a[0] * DN, x1 = a[1] * DN, x2 = a[2] * DN, x3 = a[3] * DN;
      float y0 = bq[0] * DN, y1 = bq[1] * DN, y2 = bq[2] * DN, y3 = bq[3] * DN;
      avk[kk] = (f16x8){(f16)x0, (f16)x1, (f16)x2, (f16)x3,
                        (f16)y0, (f16)y1, (f16)y2, (f16)y3};
      kdl += x0 * x0 + x1 * x1 + x2 * x2 + x3 * x3 + y0 * y0 + y1 * y1 + y2 * y2 + y3 * y3;
    }
    kdl *= 0.5f;
    kdl += __shfl_xor(kdl, 16);
    kdl += __shfl_xor(kdl, 32);
    if (cH == 0) {
      f16* ko = ksh + (size_t)(bh * T_ + trow) * E_;
      *(f16x8*)(ko + g4 * 8) = avk[0];
      *(f16x8*)(ko + 32 + g4 * 8) = avk[1];
      if (l < 16) kd[bh * T_ + trow] = kdl;
    }
    f32x4 acc[8];
#pragma unroll
    for (int ct = 0; ct < 8; ++ct) acc[ct] = (f32x4){0.f, 0.f, 0.f, 0.f};
#pragma unroll
    for (int kk = 0; kk < 2; ++kk)
#pragma unroll
      for (int ct = 0; ct < 8; ++ct) {
        int m = cH * 128 + ct * 16 + l15;
        f16x8 bv = *(const f16x8*)(projh + (size_t)m * E_ + kk * 32 + g4 * 8);
        acc[ct] = MFMA16(avk[kk], bv, acc[ct]);
      }
    float kd4[4];
#pragma unroll
    for (int r = 0; r < 4; ++r) kd4[r] = __shfl(kdl, (l & 48) + g4 * 4 + r);
#pragma unroll
    for (int ct = 0; ct < 8; ++ct)
#pragma unroll
      for (int r = 0; r < 4; ++r) lmax = fmaxf(lmax, acc[ct][r] - kd4[r]);
  }
#pragma unroll
  for (int off = 32; off; off >>= 1) lmax = fmaxf(lmax, __shfl_xor(lmax, off));
  if (l == 0) red[w] = lmax;
  __syncthreads();
  if (t == 0) {
    float mm = red[0];
#pragma unroll
    for (int ww = 1; ww < 8; ++ww) mm = fmaxf(mm, red[ww]);
    atomicMax(skb + bh, fkey(mm));
  }
}

// kpv: k_prime = 16*exp(k_shift - s_k) -> global f16; kv partial GEMM chunk;
// ALSO writes the transposed V (f16) to vTT[bh][d][t] for the fused PV.
__global__ __launch_bounds__(512) void kpv_kernel(
    const float* __restrict__ value, const f16* __restrict__ ksh,
    const float* __restrict__ kd, const f16* __restrict__ projh,
    const unsigned* __restrict__ skb, f16* __restrict__ k_prime,
    float* __restrict__ kvacc8, f16* __restrict__ vTT) {
  __shared__ f16 kpT[M_][72];
  __shared__ f16 vT[80][72];
  const int blk = blockIdx.x;  // 24 bh x 8 chunks
  const int chunk = blk & 7, bh = blk >> 3;
  const int b = bh / H_, h = bh % H_;
  const int t = threadIdx.x;
  const int w = t >> 6, l = t & 63, l15 = l & 15, g4 = l >> 4;
  const int rblk = w & 3, cH = w >> 2, r0 = rblk * 16;
  const float skv = unfkey(skb[bh]);

  for (int idx = t; idx < 16 * 72; idx += 512) {
    int rr = idx / 72, cc = idx % 72;
    vT[64 + rr][cc] = (rr == 0) ? (f16)1.0f : (f16)0.0f;
  }
  f32x4 acc[2][5];
#pragma unroll
  for (int q = 0; q < 2; ++q)
#pragma unroll
    for (int n2 = 0; n2 < 5; ++n2) acc[q][n2] = (f32x4){0.f, 0.f, 0.f, 0.f};

  for (int ti = 0; ti < 4; ++ti) {
    const int t0 = chunk * 256 + ti * 64;
    const int trow = t0 + r0 + l15;
    const f16* gk = ksh + (size_t)(bh * T_ + trow) * E_;
    f16x8 avk0 = *(const f16x8*)(gk + g4 * 8);
    f16x8 avk1 = *(const f16x8*)(gk + 32 + g4 * 8);
    f32x4 kacc[8];
#pragma unroll
    for (int ct = 0; ct < 8; ++ct) kacc[ct] = (f32x4){0.f, 0.f, 0.f, 0.f};
#pragma unroll
    for (int ct = 0; ct < 8; ++ct) {
      int m = cH * 128 + ct * 16 + l15;
      f16x8 bv0 = *(const f16x8*)(projh + (size_t)m * E_ + g4 * 8);
      f16x8 bv1 = *(const f16x8*)(projh + (size_t)m * E_ + 32 + g4 * 8);
      kacc[ct] = MFMA16(avk0, bv0, kacc[ct]);
      kacc[ct] = MFMA16(avk1, bv1, kacc[ct]);
    }
    float kd4[4];
#pragma unroll
    for (int r = 0; r < 4; ++r) kd4[r] = kd[bh * T_ + t0 + r0 + g4 * 4 + r];
    __syncthreads();  // prev ti GEMM reads done
    const int tloc = r0 + g4 * 4;
    const int uw = tloc >> 3, off = tloc & 7;
#pragma unroll
    for (int ct = 0; ct < 8; ++ct) {
      int m = cH * 128 + ct * 16 + l15;
      f16x4 pk;
#pragma unroll
      for (int r = 0; r < 4; ++r) {
        float kp = __expf(kacc[ct][r] - kd4[r] - skv + LN_CK);
        pk[r] = (f16)kp;
        k_prime[((size_t)bh * T_ + t0 + tloc + r) * M_ + m] = pk[r];
      }
      *(f16x4*)&kpT[m][(uw ^ ((m >> 1) & 7)) * 8 + off] = pk;
    }
    {
      int d = l, t8 = w;
      const float* gv = value + (((size_t)b * T_ + t0 + t8 * 8) * H_ + h) * E_ + d;
      f16x8 a;
#pragma unroll
      for (int r = 0; r < 8; ++r) a[r] = (f16)gv[(size_t)r * H_ * E_];
      *(f16x8*)&vT[d][(t8 ^ ((d >> 1) & 7)) * 8] = a;
    }
    __syncthreads();
    // write transposed V chunk to vTT (linear [d][t])
    {
      int d2 = t >> 3, t8 = t & 7;
      f16x8 vv = *(const f16x8*)&vT[d2][(t8 ^ ((d2 >> 1) & 7)) * 8];
      *(f16x8*)(vTT + ((size_t)bh * 64 + d2) * T_ + t0 + t8 * 8) = vv;
    }
#pragma unroll
    for (int kk = 0; kk < 2; ++kk) {
      int u = kk * 4 + g4;
      f16x8 afr[2];
#pragma unroll
      for (int q = 0; q < 2; ++q) {
        int m = (w * 2 + q) * 16 + l15;
        afr[q] = *(const f16x8*)&kpT[m][(u ^ ((m >> 1) & 7)) * 8];
      }
#pragma unroll
      for (int n2 = 0; n2 < 5; ++n2) {
        int d = n2 * 16 + l15;
        f16x8 bfr = *(const f16x8*)&vT[d][(u ^ ((d >> 1) & 7)) * 8];
#pragma unroll
        for (int q = 0; q < 2; ++q) acc[q][n2] = MFMA16(afr[q], bfr, acc[q][n2]);
      }
    }
  }
#pragma unroll
  for (int q = 0; q < 2; ++q)
#pragma unroll
    for (int n2 = 0; n2 < 5; ++n2) {
      int d = n2 * 16 + l15;
      if (d < 65) {
        int m0 = (w * 2 + q) * 16 + g4 * 4;
        f32x4 st = {acc[q][n2][0], acc[q][n2][1], acc[q][n2][2], acc[q][n2][3]};
        *(f32x4*)(kvacc8 + (size_t)chunk * PSTRIDEF + ((size_t)bh * 65 + d) * M_ + m0) = st;
      }
    }
}

// reduce 8 partials -> kvT f16 (x0.25; rows 65..79 zero)
__global__ __launch_bounds__(256) void kvred_kernel(
    const float* __restrict__ kvacc8, f16* __restrict__ kvT) {
  int idx = blockIdx.x * 256 + threadIdx.x;  // 480 blocks
  int m0 = (idx & 63) * 4;
  int rd = idx >> 6;
  int bh = rd / 80, d = rd - bh * 80;
  f32x4 s = {0.f, 0.f, 0.f, 0.f};
  if (d < 65) {
    const float* p = kvacc8 + ((size_t)bh * 65 + d) * M_ + m0;
#pragma unroll
    for (int c = 0; c < 8; ++c) {
      f32x4 u = *(const f32x4*)(p + (size_t)c * PSTRIDEF);
      s[0] += u[0]; s[1] += u[1]; s[2] += u[2]; s[3] += u[3];
    }
  }
  f16x4 hv = {(f16)(0.25f * s[0]), (f16)(0.25f * s[1]),
              (f16)(0.25f * s[2]), (f16)(0.25f * s[3])};
  *(f16x4*)(kvT + ((size_t)bh * 80 + d) * M_ + m0) = hv;
}

// main2: per (b,h, 32-row group = 2 x 16-row tiles sharing the SAME windows).
// 256 thr / 4 waves. ALL address-only loads (kb, bvv, dp/qkv dbuf-0) issued
// at the top so their latency hides under the qdash/QK compute phase.
__global__ __launch_bounds__(256, 4) void main2(
    const float* __restrict__ query, const f16* __restrict__ ksh,
    const f16* __restrict__ projh, const f16* __restrict__ k_prime,
    const f16* __restrict__ kvT, const f16* __restrict__ vTT,
    const unsigned* __restrict__ skb, float* __restrict__ out) {
  __shared__ f16 qpL[2][16][264];   // q' per tile (16896 B)
  __shared__ f16 dpS[2][16][200];   // exp'd S, then dots (12800 B)
  __shared__ float wmaxq[2][16][4]; // 512 B
  __shared__ float4 mps[2][16][5];  // 2560 B   -> total 32768 B

  // XCD swizzle: 1536 = 24 x 64; 8 consecutive groups per XCD.
  const int D = blockIdx.x;
  const int L = (D & ~63) + (D & 7) * 8 + ((D & 63) >> 3);
  const int g32 = L & 63;
  const int bh = L >> 6;
  const int b = bh / H_, h = bh % H_;
  const int t0g = g32 * 32;
  const int nb = g32 >> 1;
  const int t = threadIdx.x;
  const int cq = t >> 6, l = t & 63, l15 = l & 15, g4 = l >> 4;
  const float skv = unfkey(skb[bh]);

  int tkw[3];
  bool wvalid[3];
#pragma unroll
  for (int wi = 0; wi < 3; ++wi) {
    int rbk = nb - 1 + wi;
    wvalid[wi] = (rbk >= 0) && (rbk < NBLK);
    tkw[wi] = ((rbk < 0) ? 0 : (rbk > NBLK - 1 ? NBLK - 1 : rbk)) * 64;
  }

  // ---- q frags + q_diag per tile ----
  f16x8 av_q[2][2];
  float qd[2];
#pragma unroll
  for (int ta = 0; ta < 2; ++ta) {
    float qdl = 0.f;
    const float* gq = query + (((size_t)b * T_ + t0g + ta * 16 + l15) * H_ + h) * E_;
#pragma unroll
    for (int kk = 0; kk < 2; ++kk) {
      int e0 = kk * 32 + g4 * 8;
      f32x4 a = *(const f32x4*)(gq + e0);
      f32x4 c = *(const f32x4*)(gq + e0 + 4);
      float x0 = a[0] * DN, x1 = a[1] * DN, x2 = a[2] * DN, x3 = a[3] * DN;
      float y0 = c[0] * DN, y1 = c[1] * DN, y2 = c[2] * DN, y3 = c[3] * DN;
      av_q[ta][kk] = (f16x8){(f16)x0, (f16)x1, (f16)x2, (f16)x3,
                             (f16)y0, (f16)y1, (f16)y2, (f16)y3};
      qdl += x0 * x0 + x1 * x1 + x2 * x2 + x3 * x3 + y0 * y0 + y1 * y1 + y2 * y2 + y3 * y3;
    }
    qdl *= 0.5f;
    qdl += __shfl_xor(qdl, 16);
    qdl += __shfl_xor(qdl, 32);
    qd[ta] = qdl;
  }

  // ---- ALL address-only loads issued up front (latency hidden under qdash/QK)
  f16x8 kb[6];
#pragma unroll
  for (int wi = 0; wi < 3; ++wi)
#pragma unroll
    for (int kk = 0; kk < 2; ++kk)
      kb[wi * 2 + kk] = *(const f16x8*)(ksh + (size_t)(bh * T_ + tkw[wi] + cq * 16 + l15) * E_ + kk * 32 + g4 * 8);

  f16x8 bvv[6];
#pragma unroll
  for (int kk = 0; kk < 6; ++kk)
    bvv[kk] = *(const f16x8*)(vTT + ((size_t)bh * 64 + cq * 16 + l15) * T_
                              + tkw[kk >> 1] + (kk & 1) * 32 + g4 * 8);

  const f16* kpb0 = k_prime + (size_t)(bh * T_ + tkw[0] + cq * 16 + l15) * M_ + g4 * 8;
  const f16* kpb1 = k_prime + (size_t)(bh * T_ + tkw[1] + cq * 16 + l15) * M_ + g4 * 8;
  const f16* kpb2 = k_prime + (size_t)(bh * T_ + tkw[2] + cq * 16 + l15) * M_ + g4 * 8;
  const f16* kvb0 = kvT + (size_t)(bh * 80 + cq * 16 + l15) * M_ + g4 * 8;
  const f16* kvb1 = kvT + (size_t)(bh * 80 + 64 + l15) * M_ + g4 * 8;
  f16x8 bd0[2], bd1[2], bd2[2], bq0[2], bq1[2];
  bd0[0] = *(const f16x8*)(kpb0);
  bd1[0] = *(const f16x8*)(kpb1);
  bd2[0] = *(const f16x8*)(kpb2);
  bq0[0] = *(const f16x8*)(kvb0);
  if (cq == 0) bq1[0] = *(const f16x8*)(kvb1);

  // ---- q_dash GEMM, pb loaded ONCE for both tiles ----
  f32x4 qdacc[2][4];
#pragma unroll
  for (int ta = 0; ta < 2; ++ta)
#pragma unroll
    for (int ct = 0; ct < 4; ++ct) qdacc[ta][ct] = (f32x4){0.f, 0.f, 0.f, 0.f};
#pragma unroll
  for (int ct = 0; ct < 4; ++ct)
#pragma unroll
    for (int kk = 0; kk < 2; ++kk) {
      f16x8 pb = *(const f16x8*)(projh + (size_t)(cq * 64 + ct * 16 + l15) * E_ + kk * 32 + g4 * 8);
      qdacc[0][ct] = MFMA16(pb, av_q[0][kk], qdacc[0][ct]);
      qdacc[1][ct] = MFMA16(pb, av_q[1][kk], qdacc[1][ct]);
    }
#pragma unroll
  for (int ta = 0; ta < 2; ++ta) {
    float mx = -3.0e38f;
#pragma unroll
    for (int ct = 0; ct < 4; ++ct)
#pragma unroll
      for (int r = 0; r < 4; ++r) mx = fmaxf(mx, qdacc[ta][ct][r]);
    mx = fmaxf(mx, __shfl_xor(mx, 16));
    mx = fmaxf(mx, __shfl_xor(mx, 32));
    if (l < 16) wmaxq[ta][l15][cq] = mx;
  }
  __syncthreads();  // B1

  float sq[2];
#pragma unroll
  for (int ta = 0; ta < 2; ++ta)
    sq[ta] = fmaxf(fmaxf(wmaxq[ta][l15][0], wmaxq[ta][l15][1]),
                   fmaxf(wmaxq[ta][l15][2], wmaxq[ta][l15][3]));

  // ---- q' tiles ----
#pragma unroll
  for (int ta = 0; ta < 2; ++ta)
#pragma unroll
    for (int ct = 0; ct < 4; ++ct) {
      f16x4 qp;
#pragma unroll
      for (int r = 0; r < 4; ++r) qp[r] = (f16)__expf(qdacc[ta][ct][r] - sq[ta] + LN_CQ);
      *(f16x4*)&qpL[ta][l15][cq * 64 + ct * 16 + g4 * 4] = qp;
    }

  // ---- QK GEMM (kb shared) ----
  f32x4 sacc[2][3];
#pragma unroll
  for (int ta = 0; ta < 2; ++ta)
#pragma unroll
    for (int a = 0; a < 3; ++a) sacc[ta][a] = (f32x4){0.f, 0.f, 0.f, 0.f};
#pragma unroll
  for (int wi = 0; wi < 3; ++wi)
#pragma unroll
    for (int kk = 0; kk < 2; ++kk) {
      sacc[0][wi] = MFMA16(kb[wi * 2 + kk], av_q[0][kk], sacc[0][wi]);
      sacc[1][wi] = MFMA16(kb[wi * 2 + kk], av_q[1][kk], sacc[1][wi]);
    }

  // ---- wave-local max, exp, psl; stash exp'd S to LDS (frees sacc) ----
  float mw[2], psl[2];
#pragma unroll
  for (int ta = 0; ta < 2; ++ta) {
    float mx = -3.0e38f;
#pragma unroll
    for (int wi = 0; wi < 3; ++wi)
      if (wvalid[wi])
#pragma unroll
        for (int r = 0; r < 4; ++r) mx = fmaxf(mx, sacc[ta][wi][r]);
    mx = fmaxf(mx, __shfl_xor(mx, 16));
    mx = fmaxf(mx, __shfl_xor(mx, 32));
    mw[ta] = mx;
    float ps = 0.f;
#pragma unroll
    for (int wi = 0; wi < 3; ++wi) {
      if (wvalid[wi]) {
#pragma unroll
        for (int r = 0; r < 4; ++r) {
          sacc[ta][wi][r] = __expf(sacc[ta][wi][r] - mx);
          ps += sacc[ta][wi][r];
        }
      } else {
#pragma unroll
        for (int r = 0; r < 4; ++r) sacc[ta][wi][r] = 0.f;
      }
    }
    ps += __shfl_xor(ps, 16);
    ps += __shfl_xor(ps, 32);
    psl[ta] = ps;
#pragma unroll
    for (int wi = 0; wi < 3; ++wi) {
      f16x4 sv = {(f16)sacc[ta][wi][0], (f16)sacc[ta][wi][1],
                  (f16)sacc[ta][wi][2], (f16)sacc[ta][wi][3]};
      *(f16x4*)&dpS[ta][l15][wi * 64 + cq * 16 + g4 * 4] = sv;
    }
  }
  __syncthreads();  // B2: qpL ready

  // ---- dp + qkv GEMMs: each B-frag feeds BOTH tiles ----
  f32x4 dacc[2][3], qkvA[2], qkvB[2];
#pragma unroll
  for (int ta = 0; ta < 2; ++ta) {
#pragma unroll
    for (int a = 0; a < 3; ++a) dacc[ta][a] = (f32x4){0.f, 0.f, 0.f, 0.f};
    qkvA[ta] = (f32x4){0.f, 0.f, 0.f, 0.f};
    qkvB[ta] = (f32x4){0.f, 0.f, 0.f, 0.f};
  }
#pragma unroll
  for (int kk = 0; kk < 8; ++kk) {
    const int cur = kk & 1, nxt = cur ^ 1;
    if (kk < 7) {
      const int o = (kk + 1) * 32;
      bd0[nxt] = *(const f16x8*)(kpb0 + o);
      bd1[nxt] = *(const f16x8*)(kpb1 + o);
      bd2[nxt] = *(const f16x8*)(kpb2 + o);
      bq0[nxt] = *(const f16x8*)(kvb0 + o);
      if (cq == 0) bq1[nxt] = *(const f16x8*)(kvb1 + o);
    }
#pragma unroll
    for (int ta = 0; ta < 2; ++ta) {
      f16x8 qf = *(const f16x8*)&qpL[ta][l15][kk * 32 + g4 * 8];
      dacc[ta][0] = MFMA16(bd0[cur], qf, dacc[ta][0]);
      dacc[ta][1] = MFMA16(bd1[cur], qf, dacc[ta][1]);
      dacc[ta][2] = MFMA16(bd2[cur], qf, dacc[ta][2]);
      qkvA[ta] = MFMA16(bq0[cur], qf, qkvA[ta]);
      if (cq == 0) qkvB[ta] = MFMA16(bq1[cur], qf, qkvB[ta]);
    }
  }

  // ---- zero invalid dacc, reduce dsl, publish per-wave stats ----
  float dsl[2];
#pragma unroll
  for (int ta = 0; ta < 2; ++ta) {
    float s = 0.f;
#pragma unroll
    for (int wi = 0; wi < 3; ++wi) {
      if (wvalid[wi]) {
#pragma unroll
        for (int r = 0; r < 4; ++r) s += dacc[ta][wi][r];
      } else {
#pragma unroll
        for (int r = 0; r < 4; ++r) dacc[ta][wi][r] = 0.f;
      }
    }
    s += __shfl_xor(s, 16);
    s += __shfl_xor(s, 32);
    dsl[ta] = s;
  }
  if (l < 16) {
#pragma unroll
    for (int ta = 0; ta < 2; ++ta) {
      float q1 = (cq == 0) ? 4.0f * qkvB[ta][0] : 0.f;
      mps[ta][l15][cq] = (float4){mw[ta], psl[ta], dsl[ta], q1};
    }
  }
  __syncthreads();  // B3

  // ---- per-lane stats ----
  float efac[2], psr[2];
#pragma unroll
  for (int ta = 0; ta < 2; ++ta) {
    float4 c0 = mps[ta][l15][0], c1 = mps[ta][l15][1],
           c2 = mps[ta][l15][2], c3 = mps[ta][l15][3];
    float M = fmaxf(fmaxf(c0.x, c1.x), fmaxf(c2.x, c3.x));
    float pstot = __expf(c0.x - M) * c0.y + __expf(c1.x - M) * c1.y +
                  __expf(c2.x - M) * c2.y + __expf(c3.x - M) * c3.y;
    float dsum = c0.z + c1.z + c2.z + c3.z;
    float lse = M + __logf(pstot);
    float plsC = sq[ta] - qd[ta] - HALF_LOG_M + skv - HALF_LOG_M - LN_CQ - LN_CK;
    float lr = __logf(fmaxf(c0.w - dsum, 1e-24f)) + plsC;
    float mm = fmaxf(lse, lr);
    float ln = mm + __logf(__expf(lse - mm) + __expf(lr - mm));
    efac[ta] = __expf(mw[ta] - ln);
    psr[ta] = __expf(plsC - ln);
  }

  // ---- dots: lane-private in-place update of dpS ----
#pragma unroll
  for (int ta = 0; ta < 2; ++ta)
#pragma unroll
    for (int wi = 0; wi < 3; ++wi) {
      f16x4 s4 = *(const f16x4*)&dpS[ta][l15][wi * 64 + cq * 16 + g4 * 4];
      f16x4 dv;
#pragma unroll
      for (int r = 0; r < 4; ++r)
        dv[r] = (f16)((float)s4[r] * efac[ta] - dacc[ta][wi][r] * psr[ta]);
      *(f16x4*)&dpS[ta][l15][wi * 64 + cq * 16 + g4 * 4] = dv;
    }
  __syncthreads();  // B4

  // ---- PV: C[d][i] = mfma(vT_d, dots_i); bvv shared across tiles ----
  f32x4 oacc[2];
  oacc[0] = oacc[1] = (f32x4){0.f, 0.f, 0.f, 0.f};
#pragma unroll
  for (int kk = 0; kk < 6; ++kk) {
#pragma unroll
    for (int ta = 0; ta < 2; ++ta) {
      f16x8 bp = *(const f16x8*)&dpS[ta][l15][kk * 32 + g4 * 8];
      oacc[ta] = MFMA16(bvv[kk], bp, oacc[ta]);
    }
  }
#pragma unroll
  for (int ta = 0; ta < 2; ++ta) {
    f32x4 o;
    o[0] = oacc[ta][0] + 4.0f * qkvA[ta][0] * psr[ta];
    o[1] = oacc[ta][1] + 4.0f * qkvA[ta][1] * psr[ta];
    o[2] = oacc[ta][2] + 4.0f * qkvA[ta][2] * psr[ta];
    o[3] = oacc[ta][3] + 4.0f * qkvA[ta][3] * psr[ta];
    *(f32x4*)(out + (((size_t)b * T_ + t0g + ta * 16 + l15) * H_ + h) * E_ + cq * 16 + g4 * 4) = o;
  }
}

extern "C" void kernel_launch(void* const* d_in, const int* in_sizes, int n_in,
                              void* d_out, int out_size, void* d_ws, size_t ws_size,
                              hipStream_t stream) {
  const float* query = (const float*)d_in[0];
  const float* key   = (const float*)d_in[1];
  const float* value = (const float*)d_in[2];
  const float* proj  = (const float*)d_in[3];
  float* out = (float*)d_out;

  char* ws = (char*)d_ws;
  unsigned* skb = (unsigned*)ws;
  f16* projh    = (f16*)(ws + 256);
  f16* ksh      = (f16*)(ws + 33024);
  float* kd     = (float*)(ws + 6324480);
  f16* k_prime  = (f16*)(ws + 6521088);
  f16* vTT      = (f16*)(ws + 31686912);
  float* kvacc8 = (float*)(ws + 37978368);
  f16* kvT      = (f16*)(ws + 50757888);

  init_ws<<<64, 256, 0, stream>>>(skb, projh, proj);
  prep_k<<<B_ * H_ * 8, 512, 0, stream>>>(key, projh, skb, ksh, kd);
  kpv_kernel<<<B_ * H_ * 8, 512, 0, stream>>>(value, ksh, kd, projh, skb, k_prime, kvacc8, vTT);
  kvred_kernel<<<480, 256, 0, stream>>>(kvacc8, kvT);
  main2<<<B_ * H_ * 64, 256, 0, stream>>>(query, ksh, projh, k_prime, kvT, vTT, skb, out);
}

// Round 17
// 96.918 us; speedup vs baseline: 1.0825x; 1.0825x over previous
//
#include <hip/hip_runtime.h>

#define B_ 2
#define T_ 2048
#define H_ 12
#define E_ 64
#define M_ 256
#define NBLK 32

typedef _Float16 f16;
typedef f16 f16x4 __attribute__((ext_vector_type(4)));
typedef f16 f16x8 __attribute__((ext_vector_type(8)));
typedef float f32x4 __attribute__((ext_vector_type(4)));

#define MFMA16(Av, Bv, Cv) __builtin_amdgcn_mfma_f32_16x16x32_f16(Av, Bv, Cv, 0, 0, 0)

constexpr float DN = 0.35355339059327373f;        // sqrt(temp)
constexpr float HALF_LOG_M = 2.7725887222397811f; // 0.5*ln(256)
constexpr float LN_CQ = 5.545177444479562f;       // ln(256): q' scale
constexpr float LN_CK = 2.772588722239781f;       // ln(16):  k' scale

__device__ __forceinline__ unsigned fkey(float f) {
  unsigned u = __float_as_uint(f);
  return (u & 0x80000000u) ? ~u : (u | 0x80000000u);
}
__device__ __forceinline__ float unfkey(unsigned k) {
  return (k & 0x80000000u) ? __uint_as_float(k & 0x7fffffffu) : __uint_as_float(~k);
}

// ---------------- workspace layout (bytes) ----------------
// 0         : skb     uint[24]                        (pad 256)
// 256       : projh   f16 [256][64]         32768 ->     33024
// 33024     : ksh     f16 [24][2048][64]  6291456 ->   6324480
// 6324480   : kd      f32 [24][2048]       196608 ->   6521088
// 6521088   : k_prime f16 [24][2048][256] 25165824 -> 31686912
// 31686912  : vTT     f16 [24][64][2048]  6291456 ->  37978368
// 37978368  : kvacc8  f32 [8][24][65][256] 12779520 -> 50757888
// 50757888  : kvT     f16 [24][80][256]     983040 ->  51740928  (< proven 52.13 MB)
#define PSTRIDEF 399360  // 24*65*256 floats per partial

__global__ void init_ws(unsigned* __restrict__ skb, f16* __restrict__ projh,
                        const float* __restrict__ proj) {
  int i = blockIdx.x * blockDim.x + threadIdx.x;
  if (i < B_ * H_) skb[i] = 0u;
  if (i < M_ * E_) projh[i] = (f16)proj[i];
}

// prep_k: store ksh (DN-scaled f16) + kd (f32); GEMM k_dash; global max -> skb
__global__ __launch_bounds__(512) void prep_k(
    const float* __restrict__ key, const f16* __restrict__ projh,
    unsigned* __restrict__ skb, f16* __restrict__ ksh, float* __restrict__ kd) {
  __shared__ float red[8];
  const int blk = blockIdx.x;  // 24 bh x 8 chunks
  const int chunk = blk & 7, bh = blk >> 3;
  const int b = bh / H_, h = bh % H_;
  const int t = threadIdx.x;
  const int w = t >> 6, l = t & 63, l15 = l & 15, g4 = l >> 4;
  const int rblk = w & 3, cH = w >> 2, r0 = rblk * 16;
  float lmax = -3.0e38f;

  for (int ti = 0; ti < 4; ++ti) {
    const int t0 = chunk * 256 + ti * 64;
    const int trow = t0 + r0 + l15;
    f16x8 avk[2];
    float kdl = 0.f;
    const float* gk = key + (((size_t)b * T_ + trow) * H_ + h) * E_;
#pragma unroll
    for (int kk = 0; kk < 2; ++kk) {
      int e0 = kk * 32 + g4 * 8;
      f32x4 a = *(const f32x4*)(gk + e0);
      f32x4 bq = *(const f32x4*)(gk + e0 + 4);
      float x0 = a[0] * DN, x1 = a[1] * DN, x2 = a[2] * DN, x3 = a[3] * DN;
      float y0 = bq[0] * DN, y1 = bq[1] * DN, y2 = bq[2] * DN, y3 = bq[3] * DN;
      avk[kk] = (f16x8){(f16)x0, (f16)x1, (f16)x2, (f16)x3,
                        (f16)y0, (f16)y1, (f16)y2, (f16)y3};
      kdl += x0 * x0 + x1 * x1 + x2 * x2 + x3 * x3 + y0 * y0 + y1 * y1 + y2 * y2 + y3 * y3;
    }
    kdl *= 0.5f;
    kdl += __shfl_xor(kdl, 16);
    kdl += __shfl_xor(kdl, 32);
    if (cH == 0) {
      f16* ko = ksh + (size_t)(bh * T_ + trow) * E_;
      *(f16x8*)(ko + g4 * 8) = avk[0];
      *(f16x8*)(ko + 32 + g4 * 8) = avk[1];
      if (l < 16) kd[bh * T_ + trow] = kdl;
    }
    f32x4 acc[8];
#pragma unroll
    for (int ct = 0; ct < 8; ++ct) acc[ct] = (f32x4){0.f, 0.f, 0.f, 0.f};
#pragma unroll
    for (int kk = 0; kk < 2; ++kk)
#pragma unroll
      for (int ct = 0; ct < 8; ++ct) {
        int m = cH * 128 + ct * 16 + l15;
        f16x8 bv = *(const f16x8*)(projh + (size_t)m * E_ + kk * 32 + g4 * 8);
        acc[ct] = MFMA16(avk[kk], bv, acc[ct]);
      }
    float kd4[4];
#pragma unroll
    for (int r = 0; r < 4; ++r) kd4[r] = __shfl(kdl, (l & 48) + g4 * 4 + r);
#pragma unroll
    for (int ct = 0; ct < 8; ++ct)
#pragma unroll
      for (int r = 0; r < 4; ++r) lmax = fmaxf(lmax, acc[ct][r] - kd4[r]);
  }
#pragma unroll
  for (int off = 32; off; off >>= 1) lmax = fmaxf(lmax, __shfl_xor(lmax, off));
  if (l == 0) red[w] = lmax;
  __syncthreads();
  if (t == 0) {
    float mm = red[0];
#pragma unroll
    for (int ww = 1; ww < 8; ++ww) mm = fmaxf(mm, red[ww]);
    atomicMax(skb + bh, fkey(mm));
  }
}

// kpv: k_prime = 16*exp(k_shift - s_k) -> global f16; kv partial GEMM chunk;
// ALSO writes the transposed V (f16) to vTT[bh][d][t] for the fused PV.
__global__ __launch_bounds__(512) void kpv_kernel(
    const float* __restrict__ value, const f16* __restrict__ ksh,
    const float* __restrict__ kd, const f16* __restrict__ projh,
    const unsigned* __restrict__ skb, f16* __restrict__ k_prime,
    float* __restrict__ kvacc8, f16* __restrict__ vTT) {
  __shared__ f16 kpT[M_][72];
  __shared__ f16 vT[80][72];
  const int blk = blockIdx.x;  // 24 bh x 8 chunks
  const int chunk = blk & 7, bh = blk >> 3;
  const int b = bh / H_, h = bh % H_;
  const int t = threadIdx.x;
  const int w = t >> 6, l = t & 63, l15 = l & 15, g4 = l >> 4;
  const int rblk = w & 3, cH = w >> 2, r0 = rblk * 16;
  const float skv = unfkey(skb[bh]);

  for (int idx = t; idx < 16 * 72; idx += 512) {
    int rr = idx / 72, cc = idx % 72;
    vT[64 + rr][cc] = (rr == 0) ? (f16)1.0f : (f16)0.0f;
  }
  f32x4 acc[2][5];
#pragma unroll
  for (int q = 0; q < 2; ++q)
#pragma unroll
    for (int n2 = 0; n2 < 5; ++n2) acc[q][n2] = (f32x4){0.f, 0.f, 0.f, 0.f};

  for (int ti = 0; ti < 4; ++ti) {
    const int t0 = chunk * 256 + ti * 64;
    const int trow = t0 + r0 + l15;
    const f16* gk = ksh + (size_t)(bh * T_ + trow) * E_;
    f16x8 avk0 = *(const f16x8*)(gk + g4 * 8);
    f16x8 avk1 = *(const f16x8*)(gk + 32 + g4 * 8);
    f32x4 kacc[8];
#pragma unroll
    for (int ct = 0; ct < 8; ++ct) kacc[ct] = (f32x4){0.f, 0.f, 0.f, 0.f};
#pragma unroll
    for (int ct = 0; ct < 8; ++ct) {
      int m = cH * 128 + ct * 16 + l15;
      f16x8 bv0 = *(const f16x8*)(projh + (size_t)m * E_ + g4 * 8);
      f16x8 bv1 = *(const f16x8*)(projh + (size_t)m * E_ + 32 + g4 * 8);
      kacc[ct] = MFMA16(avk0, bv0, kacc[ct]);
      kacc[ct] = MFMA16(avk1, bv1, kacc[ct]);
    }
    float kd4[4];
#pragma unroll
    for (int r = 0; r < 4; ++r) kd4[r] = kd[bh * T_ + t0 + r0 + g4 * 4 + r];
    __syncthreads();  // prev ti GEMM reads done
    const int tloc = r0 + g4 * 4;
    const int uw = tloc >> 3, off = tloc & 7;
#pragma unroll
    for (int ct = 0; ct < 8; ++ct) {
      int m = cH * 128 + ct * 16 + l15;
      f16x4 pk;
#pragma unroll
      for (int r = 0; r < 4; ++r) {
        float kp = __expf(kacc[ct][r] - kd4[r] - skv + LN_CK);
        pk[r] = (f16)kp;
        k_prime[((size_t)bh * T_ + t0 + tloc + r) * M_ + m] = pk[r];
      }
      *(f16x4*)&kpT[m][(uw ^ ((m >> 1) & 7)) * 8 + off] = pk;
    }
    {
      int d = l, t8 = w;
      const float* gv = value + (((size_t)b * T_ + t0 + t8 * 8) * H_ + h) * E_ + d;
      f16x8 a;
#pragma unroll
      for (int r = 0; r < 8; ++r) a[r] = (f16)gv[(size_t)r * H_ * E_];
      *(f16x8*)&vT[d][(t8 ^ ((d >> 1) & 7)) * 8] = a;
    }
    __syncthreads();
    // write transposed V chunk to vTT (linear [d][t])
    {
      int d2 = t >> 3, t8 = t & 7;
      f16x8 vv = *(const f16x8*)&vT[d2][(t8 ^ ((d2 >> 1) & 7)) * 8];
      *(f16x8*)(vTT + ((size_t)bh * 64 + d2) * T_ + t0 + t8 * 8) = vv;
    }
#pragma unroll
    for (int kk = 0; kk < 2; ++kk) {
      int u = kk * 4 + g4;
      f16x8 afr[2];
#pragma unroll
      for (int q = 0; q < 2; ++q) {
        int m = (w * 2 + q) * 16 + l15;
        afr[q] = *(const f16x8*)&kpT[m][(u ^ ((m >> 1) & 7)) * 8];
      }
#pragma unroll
      for (int n2 = 0; n2 < 5; ++n2) {
        int d = n2 * 16 + l15;
        f16x8 bfr = *(const f16x8*)&vT[d][(u ^ ((d >> 1) & 7)) * 8];
#pragma unroll
        for (int q = 0; q < 2; ++q) acc[q][n2] = MFMA16(afr[q], bfr, acc[q][n2]);
      }
    }
  }
#pragma unroll
  for (int q = 0; q < 2; ++q)
#pragma unroll
    for (int n2 = 0; n2 < 5; ++n2) {
      int d = n2 * 16 + l15;
      if (d < 65) {
        int m0 = (w * 2 + q) * 16 + g4 * 4;
        f32x4 st = {acc[q][n2][0], acc[q][n2][1], acc[q][n2][2], acc[q][n2][3]};
        *(f32x4*)(kvacc8 + (size_t)chunk * PSTRIDEF + ((size_t)bh * 65 + d) * M_ + m0) = st;
      }
    }
}

// reduce 8 partials -> kvT f16 (x0.25; rows 65..79 zero)
__global__ __launch_bounds__(256) void kvred_kernel(
    const float* __restrict__ kvacc8, f16* __restrict__ kvT) {
  int idx = blockIdx.x * 256 + threadIdx.x;  // 480 blocks
  int m0 = (idx & 63) * 4;
  int rd = idx >> 6;
  int bh = rd / 80, d = rd - bh * 80;
  f32x4 s = {0.f, 0.f, 0.f, 0.f};
  if (d < 65) {
    const float* p = kvacc8 + ((size_t)bh * 65 + d) * M_ + m0;
#pragma unroll
    for (int c = 0; c < 8; ++c) {
      f32x4 u = *(const f32x4*)(p + (size_t)c * PSTRIDEF);
      s[0] += u[0]; s[1] += u[1]; s[2] += u[2]; s[3] += u[3];
    }
  }
  f16x4 hv = {(f16)(0.25f * s[0]), (f16)(0.25f * s[1]),
              (f16)(0.25f * s[2]), (f16)(0.25f * s[3])};
  *(f16x4*)(kvT + ((size_t)bh * 80 + d) * M_ + m0) = hv;
}

// main2: per (b,h, 32-row group = 2 x 16-row tiles sharing the SAME windows).
// 256 thr / 4 waves. LDS 32768 B. Loads at dependency-natural positions
// (proven round-15 configuration, 55.2 us).
__global__ __launch_bounds__(256, 4) void main2(
    const float* __restrict__ query, const f16* __restrict__ ksh,
    const f16* __restrict__ projh, const f16* __restrict__ k_prime,
    const f16* __restrict__ kvT, const f16* __restrict__ vTT,
    const unsigned* __restrict__ skb, float* __restrict__ out) {
  __shared__ f16 qpL[2][16][264];   // q' per tile (16896 B)
  __shared__ f16 dpS[2][16][200];   // exp'd S, then dots (12800 B)
  __shared__ float wmaxq[2][16][4]; // 512 B
  __shared__ float4 mps[2][16][5];  // 2560 B   -> total 32768 B

  // XCD swizzle: 1536 = 24 x 64; 8 consecutive groups per XCD.
  const int D = blockIdx.x;
  const int L = (D & ~63) + (D & 7) * 8 + ((D & 63) >> 3);
  const int g32 = L & 63;
  const int bh = L >> 6;
  const int b = bh / H_, h = bh % H_;
  const int t0g = g32 * 32;
  const int nb = g32 >> 1;
  const int t = threadIdx.x;
  const int cq = t >> 6, l = t & 63, l15 = l & 15, g4 = l >> 4;
  const float skv = unfkey(skb[bh]);

  int tkw[3];
  bool wvalid[3];
#pragma unroll
  for (int wi = 0; wi < 3; ++wi) {
    int rbk = nb - 1 + wi;
    wvalid[wi] = (rbk >= 0) && (rbk < NBLK);
    tkw[wi] = ((rbk < 0) ? 0 : (rbk > NBLK - 1 ? NBLK - 1 : rbk)) * 64;
  }

  // ---- q frags + q_diag per tile ----
  f16x8 av_q[2][2];
  float qd[2];
#pragma unroll
  for (int ta = 0; ta < 2; ++ta) {
    float qdl = 0.f;
    const float* gq = query + (((size_t)b * T_ + t0g + ta * 16 + l15) * H_ + h) * E_;
#pragma unroll
    for (int kk = 0; kk < 2; ++kk) {
      int e0 = kk * 32 + g4 * 8;
      f32x4 a = *(const f32x4*)(gq + e0);
      f32x4 c = *(const f32x4*)(gq + e0 + 4);
      float x0 = a[0] * DN, x1 = a[1] * DN, x2 = a[2] * DN, x3 = a[3] * DN;
      float y0 = c[0] * DN, y1 = c[1] * DN, y2 = c[2] * DN, y3 = c[3] * DN;
      av_q[ta][kk] = (f16x8){(f16)x0, (f16)x1, (f16)x2, (f16)x3,
                             (f16)y0, (f16)y1, (f16)y2, (f16)y3};
      qdl += x0 * x0 + x1 * x1 + x2 * x2 + x3 * x3 + y0 * y0 + y1 * y1 + y2 * y2 + y3 * y3;
    }
    qdl *= 0.5f;
    qdl += __shfl_xor(qdl, 16);
    qdl += __shfl_xor(qdl, 32);
    qd[ta] = qdl;
  }

  // ---- QK A-frags (shared by both tiles) issued early ----
  f16x8 kb[6];
#pragma unroll
  for (int wi = 0; wi < 3; ++wi)
#pragma unroll
    for (int kk = 0; kk < 2; ++kk)
      kb[wi * 2 + kk] = *(const f16x8*)(ksh + (size_t)(bh * T_ + tkw[wi] + cq * 16 + l15) * E_ + kk * 32 + g4 * 8);

  // ---- q_dash GEMM, pb loaded ONCE for both tiles ----
  f32x4 qdacc[2][4];
#pragma unroll
  for (int ta = 0; ta < 2; ++ta)
#pragma unroll
    for (int ct = 0; ct < 4; ++ct) qdacc[ta][ct] = (f32x4){0.f, 0.f, 0.f, 0.f};
#pragma unroll
  for (int ct = 0; ct < 4; ++ct)
#pragma unroll
    for (int kk = 0; kk < 2; ++kk) {
      f16x8 pb = *(const f16x8*)(projh + (size_t)(cq * 64 + ct * 16 + l15) * E_ + kk * 32 + g4 * 8);
      qdacc[0][ct] = MFMA16(pb, av_q[0][kk], qdacc[0][ct]);
      qdacc[1][ct] = MFMA16(pb, av_q[1][kk], qdacc[1][ct]);
    }
#pragma unroll
  for (int ta = 0; ta < 2; ++ta) {
    float mx = -3.0e38f;
#pragma unroll
    for (int ct = 0; ct < 4; ++ct)
#pragma unroll
      for (int r = 0; r < 4; ++r) mx = fmaxf(mx, qdacc[ta][ct][r]);
    mx = fmaxf(mx, __shfl_xor(mx, 16));
    mx = fmaxf(mx, __shfl_xor(mx, 32));
    if (l < 16) wmaxq[ta][l15][cq] = mx;
  }
  __syncthreads();  // B1

  float sq[2];
#pragma unroll
  for (int ta = 0; ta < 2; ++ta)
    sq[ta] = fmaxf(fmaxf(wmaxq[ta][l15][0], wmaxq[ta][l15][1]),
                   fmaxf(wmaxq[ta][l15][2], wmaxq[ta][l15][3]));

  // ---- q' tiles ----
#pragma unroll
  for (int ta = 0; ta < 2; ++ta)
#pragma unroll
    for (int ct = 0; ct < 4; ++ct) {
      f16x4 qp;
#pragma unroll
      for (int r = 0; r < 4; ++r) qp[r] = (f16)__expf(qdacc[ta][ct][r] - sq[ta] + LN_CQ);
      *(f16x4*)&qpL[ta][l15][cq * 64 + ct * 16 + g4 * 4] = qp;
    }

  // ---- QK GEMM (kb shared) ----
  f32x4 sacc[2][3];
#pragma unroll
  for (int ta = 0; ta < 2; ++ta)
#pragma unroll
    for (int a = 0; a < 3; ++a) sacc[ta][a] = (f32x4){0.f, 0.f, 0.f, 0.f};
#pragma unroll
  for (int wi = 0; wi < 3; ++wi)
#pragma unroll
    for (int kk = 0; kk < 2; ++kk) {
      sacc[0][wi] = MFMA16(kb[wi * 2 + kk], av_q[0][kk], sacc[0][wi]);
      sacc[1][wi] = MFMA16(kb[wi * 2 + kk], av_q[1][kk], sacc[1][wi]);
    }

  // ---- wave-local max, exp, psl; stash exp'd S to LDS (frees sacc) ----
  float mw[2], psl[2];
#pragma unroll
  for (int ta = 0; ta < 2; ++ta) {
    float mx = -3.0e38f;
#pragma unroll
    for (int wi = 0; wi < 3; ++wi)
      if (wvalid[wi])
#pragma unroll
        for (int r = 0; r < 4; ++r) mx = fmaxf(mx, sacc[ta][wi][r]);
    mx = fmaxf(mx, __shfl_xor(mx, 16));
    mx = fmaxf(mx, __shfl_xor(mx, 32));
    mw[ta] = mx;
    float ps = 0.f;
#pragma unroll
    for (int wi = 0; wi < 3; ++wi) {
      if (wvalid[wi]) {
#pragma unroll
        for (int r = 0; r < 4; ++r) {
          sacc[ta][wi][r] = __expf(sacc[ta][wi][r] - mx);
          ps += sacc[ta][wi][r];
        }
      } else {
#pragma unroll
        for (int r = 0; r < 4; ++r) sacc[ta][wi][r] = 0.f;
      }
    }
    ps += __shfl_xor(ps, 16);
    ps += __shfl_xor(ps, 32);
    psl[ta] = ps;
#pragma unroll
    for (int wi = 0; wi < 3; ++wi) {
      f16x4 sv = {(f16)sacc[ta][wi][0], (f16)sacc[ta][wi][1],
                  (f16)sacc[ta][wi][2], (f16)sacc[ta][wi][3]};
      *(f16x4*)&dpS[ta][l15][wi * 64 + cq * 16 + g4 * 4] = sv;
    }
  }

  // ---- dp/qkv pointers + first dbuf (in flight across B2) ----
  const f16* kpb0 = k_prime + (size_t)(bh * T_ + tkw[0] + cq * 16 + l15) * M_ + g4 * 8;
  const f16* kpb1 = k_prime + (size_t)(bh * T_ + tkw[1] + cq * 16 + l15) * M_ + g4 * 8;
  const f16* kpb2 = k_prime + (size_t)(bh * T_ + tkw[2] + cq * 16 + l15) * M_ + g4 * 8;
  const f16* kvb0 = kvT + (size_t)(bh * 80 + cq * 16 + l15) * M_ + g4 * 8;
  const f16* kvb1 = kvT + (size_t)(bh * 80 + 64 + l15) * M_ + g4 * 8;
  f16x8 bd0[2], bd1[2], bd2[2], bq0[2], bq1[2];
  bd0[0] = *(const f16x8*)(kpb0);
  bd1[0] = *(const f16x8*)(kpb1);
  bd2[0] = *(const f16x8*)(kpb2);
  bq0[0] = *(const f16x8*)(kvb0);
  if (cq == 0) bq1[0] = *(const f16x8*)(kvb1);
  __syncthreads();  // B2: qpL ready

  // ---- dp + qkv GEMMs: each B-frag feeds BOTH tiles ----
  f32x4 dacc[2][3], qkvA[2], qkvB[2];
#pragma unroll
  for (int ta = 0; ta < 2; ++ta) {
#pragma unroll
    for (int a = 0; a < 3; ++a) dacc[ta][a] = (f32x4){0.f, 0.f, 0.f, 0.f};
    qkvA[ta] = (f32x4){0.f, 0.f, 0.f, 0.f};
    qkvB[ta] = (f32x4){0.f, 0.f, 0.f, 0.f};
  }
#pragma unroll
  for (int kk = 0; kk < 8; ++kk) {
    const int cur = kk & 1, nxt = cur ^ 1;
    if (kk < 7) {
      const int o = (kk + 1) * 32;
      bd0[nxt] = *(const f16x8*)(kpb0 + o);
      bd1[nxt] = *(const f16x8*)(kpb1 + o);
      bd2[nxt] = *(const f16x8*)(kpb2 + o);
      bq0[nxt] = *(const f16x8*)(kvb0 + o);
      if (cq == 0) bq1[nxt] = *(const f16x8*)(kvb1 + o);
    }
#pragma unroll
    for (int ta = 0; ta < 2; ++ta) {
      f16x8 qf = *(const f16x8*)&qpL[ta][l15][kk * 32 + g4 * 8];
      dacc[ta][0] = MFMA16(bd0[cur], qf, dacc[ta][0]);
      dacc[ta][1] = MFMA16(bd1[cur], qf, dacc[ta][1]);
      dacc[ta][2] = MFMA16(bd2[cur], qf, dacc[ta][2]);
      qkvA[ta] = MFMA16(bq0[cur], qf, qkvA[ta]);
      if (cq == 0) qkvB[ta] = MFMA16(bq1[cur], qf, qkvB[ta]);
    }
  }

  // ---- zero invalid dacc, reduce dsl, publish per-wave stats ----
  float dsl[2];
#pragma unroll
  for (int ta = 0; ta < 2; ++ta) {
    float s = 0.f;
#pragma unroll
    for (int wi = 0; wi < 3; ++wi) {
      if (wvalid[wi]) {
#pragma unroll
        for (int r = 0; r < 4; ++r) s += dacc[ta][wi][r];
      } else {
#pragma unroll
        for (int r = 0; r < 4; ++r) dacc[ta][wi][r] = 0.f;
      }
    }
    s += __shfl_xor(s, 16);
    s += __shfl_xor(s, 32);
    dsl[ta] = s;
  }
  if (l < 16) {
#pragma unroll
    for (int ta = 0; ta < 2; ++ta) {
      float q1 = (cq == 0) ? 4.0f * qkvB[ta][0] : 0.f;
      mps[ta][l15][cq] = (float4){mw[ta], psl[ta], dsl[ta], q1};
    }
  }
  __syncthreads();  // B3

  // ---- per-lane stats ----
  float efac[2], psr[2];
#pragma unroll
  for (int ta = 0; ta < 2; ++ta) {
    float4 c0 = mps[ta][l15][0], c1 = mps[ta][l15][1],
           c2 = mps[ta][l15][2], c3 = mps[ta][l15][3];
    float M = fmaxf(fmaxf(c0.x, c1.x), fmaxf(c2.x, c3.x));
    float pstot = __expf(c0.x - M) * c0.y + __expf(c1.x - M) * c1.y +
                  __expf(c2.x - M) * c2.y + __expf(c3.x - M) * c3.y;
    float dsum = c0.z + c1.z + c2.z + c3.z;
    float lse = M + __logf(pstot);
    float plsC = sq[ta] - qd[ta] - HALF_LOG_M + skv - HALF_LOG_M - LN_CQ - LN_CK;
    float lr = __logf(fmaxf(c0.w - dsum, 1e-24f)) + plsC;
    float mm = fmaxf(lse, lr);
    float ln = mm + __logf(__expf(lse - mm) + __expf(lr - mm));
    efac[ta] = __expf(mw[ta] - ln);
    psr[ta] = __expf(plsC - ln);
  }

  // ---- PV A-frags from vTT (shared by both tiles) ----
  f16x8 bvv[6];
#pragma unroll
  for (int kk = 0; kk < 6; ++kk)
    bvv[kk] = *(const f16x8*)(vTT + ((size_t)bh * 64 + cq * 16 + l15) * T_
                              + tkw[kk >> 1] + (kk & 1) * 32 + g4 * 8);

  // ---- dots: lane-private in-place update of dpS ----
#pragma unroll
  for (int ta = 0; ta < 2; ++ta)
#pragma unroll
    for (int wi = 0; wi < 3; ++wi) {
      f16x4 s4 = *(const f16x4*)&dpS[ta][l15][wi * 64 + cq * 16 + g4 * 4];
      f16x4 dv;
#pragma unroll
      for (int r = 0; r < 4; ++r)
        dv[r] = (f16)((float)s4[r] * efac[ta] - dacc[ta][wi][r] * psr[ta]);
      *(f16x4*)&dpS[ta][l15][wi * 64 + cq * 16 + g4 * 4] = dv;
    }
  __syncthreads();  // B4

  // ---- PV: C[d][i] = mfma(vT_d, dots_i); bvv shared across tiles ----
  f32x4 oacc[2];
  oacc[0] = oacc[1] = (f32x4){0.f, 0.f, 0.f, 0.f};
#pragma unroll
  for (int kk = 0; kk < 6; ++kk) {
#pragma unroll
    for (int ta = 0; ta < 2; ++ta) {
      f16x8 bp = *(const f16x8*)&dpS[ta][l15][kk * 32 + g4 * 8];
      oacc[ta] = MFMA16(bvv[kk], bp, oacc[ta]);
    }
  }
#pragma unroll
  for (int ta = 0; ta < 2; ++ta) {
    f32x4 o;
    o[0] = oacc[ta][0] + 4.0f * qkvA[ta][0] * psr[ta];
    o[1] = oacc[ta][1] + 4.0f * qkvA[ta][1] * psr[ta];
    o[2] = oacc[ta][2] + 4.0f * qkvA[ta][2] * psr[ta];
    o[3] = oacc[ta][3] + 4.0f * qkvA[ta][3] * psr[ta];
    *(f32x4*)(out + (((size_t)b * T_ + t0g + ta * 16 + l15) * H_ + h) * E_ + cq * 16 + g4 * 4) = o;
  }
}

extern "C" void kernel_launch(void* const* d_in, const int* in_sizes, int n_in,
                              void* d_out, int out_size, void* d_ws, size_t ws_size,
                              hipStream_t stream) {
  const float* query = (const float*)d_in[0];
  const float* key   = (const float*)d_in[1];
  const float* value = (const float*)d_in[2];
  const float* proj  = (const float*)d_in[3];
  float* out = (float*)d_out;

  char* ws = (char*)d_ws;
  unsigned* skb = (unsigned*)ws;
  f16* projh    = (f16*)(ws + 256);
  f16* ksh      = (f16*)(ws + 33024);
  float* kd     = (float*)(ws + 6324480);
  f16* k_prime  = (f16*)(ws + 6521088);
  f16* vTT      = (f16*)(ws + 31686912);
  float* kvacc8 = (float*)(ws + 37978368);
  f16* kvT      = (f16*)(ws + 50757888);

  init_ws<<<64, 256, 0, stream>>>(skb, projh, proj);
  prep_k<<<B_ * H_ * 8, 512, 0, stream>>>(key, projh, skb, ksh, kd);
  kpv_kernel<<<B_ * H_ * 8, 512, 0, stream>>>(value, ksh, kd, projh, skb, k_prime, kvacc8, vTT);
  kvred_kernel<<<480, 256, 0, stream>>>(kvacc8, kvT);
  main2<<<B_ * H_ * 64, 256, 0, stream>>>(query, ksh, projh, k_prime, kvT, vTT, skb, out);
}